// Round 5
// baseline (18510.864 us; speedup 1.0000x reference)
//
#include <hip/hip_runtime.h>
#include <cmath>

// ESN forward scan on MI355X — round 5.
// Round-4 lesson: halving poll traffic + packing publishes REGRESSED (16.3
// -> 18.2 ms) — transaction pressure was not the governor. The common
// structure of rounds 2-4 is monolithic waiting: no wave computes until ALL
// 4096 h values arrived, and per-step __syncthreads couples wave skew into
// the chain (critical path = max over 1024 waves, every step).
// Round-5: barrier-FREE step loop with chunk-granular overlap.
//   - Each lane polls one block's 32-B slice, per-lane early exit (done
//     lanes masked off; poll traffic decays as slices arrive).
//   - hl double-buffered (16 KB) -> trailing barrier eliminated.
//   - Leading barrier -> per-chunk LDS ready flags (8 chunks x 512 rows;
//     wave w validates chunks 2w/2w+1, release-stores a monotone step
//     marker; consumers acquire-spin per chunk, accumulate partial dots as
//     chunks arrive). Serial remainder = last chunk's 512-MAC slice only.
//   - tanh via __expf (libm tanhf's branchy path was on the critical path);
//     out stores nontemporal (no write-allocate RFO); publish before out.
// Unchanged: (tag<<14)-in-fp16-bit14 exchange (|h|<1 so bit14 is free),
// ping-pong by step parity, relaxed AGENT atomics, Wh fp16 in 128
// VGPRs/thread, fp32 leak chain, cooperative launch.

#define T_STEPS  4096
#define R_SIZE   4096
#define I_SIZE   3
#define OUT_COLS (R_SIZE + I_SIZE)   // 4099
#define NB       256                 // blocks == CUs; all co-resident
#define BT       256                 // threads per block (4 waves)
#define RPB      16                  // rows per block
#define RPW      4                   // rows per wave
#define LEAK     0.1f
#define TAG_MASK 0x40004000u         // bit14 of each fp16 half

typedef _Float16 h2 __attribute__((ext_vector_type(2)));
typedef _Float16 h8 __attribute__((ext_vector_type(8)));
typedef unsigned u32x2 __attribute__((ext_vector_type(2)));
typedef unsigned u32x4 __attribute__((ext_vector_type(4)));

__device__ __forceinline__ float fdot2f(h2 a, h2 b, float c) {
#if __has_builtin(__builtin_amdgcn_fdot2)
    return __builtin_amdgcn_fdot2(a, b, c, false);
#else
    return c + (float)a[0] * (float)b[0] + (float)a[1] * (float)b[1];
#endif
}

// 8 dwords (16 rows) in flight with L1/L2 bypass, one waitcnt.
// Executed under the current exec mask: lanes already done issue nothing.
__device__ __forceinline__ void poll8(const unsigned* p, u32x4& a0, u32x4& a1) {
    asm volatile(
        "global_load_dwordx4 %0, %2, off sc0 sc1\n\t"
        "global_load_dwordx4 %1, %2, off offset:16 sc0 sc1\n\t"
        "s_waitcnt vmcnt(0)"
        : "=&v"(a0), "=&v"(a1)
        : "v"(p)
        : "memory");
}

__global__ void __launch_bounds__(BT, 1) esn_kernel(
    const float* __restrict__ Wh,   // [R, R] row-major fp32
    const float* __restrict__ Win,  // [R, 3]
    const float* __restrict__ x,    // [T, 3]
    float* __restrict__ out,        // [T, 4099]
    unsigned* __restrict__ ex0,     // exchange buf A: 2048 dwords (2 B/row)
    unsigned* __restrict__ ex1)     // exchange buf B: 2048 dwords
{
    __shared__ alignas(16) _Float16 hl[2][R_SIZE];  // 16 KB, ping-pong
    __shared__ int cflag[2][8];                     // chunk-ready step marker

    const int tid  = threadIdx.x;
    const int bid  = blockIdx.x;
    const int wv   = tid >> 6;
    const int lane = tid & 63;
    const int r0   = bid * RPB;

    // ---- one-time: this wave's 4 Wh rows -> fp16 registers ----
    h8 wreg[RPW * 8];
    #pragma unroll
    for (int rr = 0; rr < RPW; ++rr) {
        const float* src = Wh + (size_t)(r0 + wv * RPW + rr) * R_SIZE;
        #pragma unroll
        for (int j = 0; j < 8; ++j) {
            int e = (j * 64 + lane) * 8;
            float4 a = *(const float4*)(src + e);
            float4 b = *(const float4*)(src + e + 4);
            h8 hv;
            hv[0] = (_Float16)a.x; hv[1] = (_Float16)a.y;
            hv[2] = (_Float16)a.z; hv[3] = (_Float16)a.w;
            hv[4] = (_Float16)b.x; hv[5] = (_Float16)b.y;
            hv[6] = (_Float16)b.z; hv[7] = (_Float16)b.w;
            wreg[rr * 8 + j] = hv;
        }
    }

    // publisher lanes (lane<4) cache their row's Win
    float win0 = 0.f, win1 = 0.f, win2 = 0.f;
    if (lane < RPW) {
        int r = r0 + wv * RPW + lane;
        win0 = Win[(size_t)r * I_SIZE + 0];
        win1 = Win[(size_t)r * I_SIZE + 1];
        win2 = Win[(size_t)r * I_SIZE + 2];
    }
    float hown = 0.0f;   // fp32 leak chain, h0 = 0

    // thread tid polls block tid's publication: dwords [tid*8, tid*8+8)
    const unsigned* pr[2] = { ex0 + tid * 8, ex1 + tid * 8 };

    if (tid < 16) cflag[tid >> 3][tid & 7] = -1;
    __syncthreads();   // once, before the step loop

    for (int t = 0; t < T_STEPS; ++t) {
        const int par = t & 1;
        unsigned* __restrict__ exw = par ? ex0 : ex1;       // buffer (t+1)&1
        const unsigned tagexp = ((unsigned)t >> 1) & 1u;
        const unsigned tagbit = (((unsigned)t + 1u) >> 1) & 1u;

        const float xt0 = x[t * 3 + 0];
        const float xt1 = x[t * 3 + 1];
        const float xt2 = x[t * 3 + 2];

        // ---- per-lane poll with early exit (done lanes stop loading) ----
        u32x4 a0, a1;
        bool done = false;
        while (!done) {
            poll8(pr[par], a0, a1);
            unsigned andv = a0[0] & a0[1] & a0[2] & a0[3]
                          & a1[0] & a1[1] & a1[2] & a1[3];
            unsigned orv  = a0[0] | a0[1] | a0[2] | a0[3]
                          | a1[0] | a1[1] | a1[2] | a1[3];
            done = tagexp ? ((andv & TAG_MASK) == TAG_MASK)
                          : ((orv  & TAG_MASK) == 0u);
            if (!done) __builtin_amdgcn_s_sleep(2);
        }

        // ---- strip tags, stage 32 B to LDS (parity buffer) ----
        {
            u32x4 s0, s1;
            #pragma unroll
            for (int i = 0; i < 4; ++i) { s0[i] = a0[i] & ~TAG_MASK;
                                          s1[i] = a1[i] & ~TAG_MASK; }
            u32x4* d = (u32x4*)&hl[par][(unsigned)tid * 16];
            d[0] = s0; d[1] = s1;
        }

        // ---- mark this wave's two chunks ready (release: drains ds queue) ----
        if (lane == 0) {
            __hip_atomic_store(&cflag[par][2 * wv], t,
                               __ATOMIC_RELEASE, __HIP_MEMORY_SCOPE_WORKGROUP);
            __hip_atomic_store(&cflag[par][2 * wv + 1], t,
                               __ATOMIC_RELEASE, __HIP_MEMORY_SCOPE_WORKGROUP);
        }

        // ---- dots, chunk-gated: accumulate as chunks become ready ----
        float acc[RPW] = {0.f, 0.f, 0.f, 0.f};
        #pragma unroll
        for (int j = 0; j < 8; ++j) {
            if ((j >> 1) != wv) {   // own chunks are already ready (uniform branch)
                while (__hip_atomic_load(&cflag[par][j],
                                         __ATOMIC_ACQUIRE,
                                         __HIP_MEMORY_SCOPE_WORKGROUP) != t)
                    __builtin_amdgcn_s_sleep(1);
            }
            h8 hh = *(const h8*)&hl[par][(unsigned)(j * 64 + lane) * 8];
            #pragma unroll
            for (int rr = 0; rr < RPW; ++rr) {
                h8 w8 = wreg[rr * 8 + j];
                acc[rr] = fdot2f(__builtin_shufflevector(w8, w8, 0, 1),
                                 __builtin_shufflevector(hh, hh, 0, 1), acc[rr]);
                acc[rr] = fdot2f(__builtin_shufflevector(w8, w8, 2, 3),
                                 __builtin_shufflevector(hh, hh, 2, 3), acc[rr]);
                acc[rr] = fdot2f(__builtin_shufflevector(w8, w8, 4, 5),
                                 __builtin_shufflevector(hh, hh, 4, 5), acc[rr]);
                acc[rr] = fdot2f(__builtin_shufflevector(w8, w8, 6, 7),
                                 __builtin_shufflevector(hh, hh, 6, 7), acc[rr]);
            }
        }
        #pragma unroll
        for (int rr = 0; rr < RPW; ++rr) {
            #pragma unroll
            for (int s = 32; s; s >>= 1) acc[rr] += __shfl_xor(acc[rr], s, 64);
        }

        // ---- epilogue: finish rows, publish FIRST, then write out ----
        float hv = 0.0f;
        unsigned hw = 0;
        if (lane < RPW) {
            float a = (lane == 0) ? acc[0]
                    : (lane == 1) ? acc[1]
                    : (lane == 2) ? acc[2] : acc[3];
            float z  = xt0 * win0 + xt1 * win1 + xt2 * win2 + a;
            float e  = __expf(2.0f * z);                 // tanh = 1 - 2/(e+1)
            float hn = 1.0f - __fdividef(2.0f, e + 1.0f);
            hv = LEAK * hown + (1.0f - LEAK) * hn;       // |hv| < 1 by induction
            hown = hv;
            unsigned short hb = __builtin_bit_cast(unsigned short, (_Float16)hv);
            hw = (unsigned)hb | (tagbit << 14);
        }
        unsigned s0 = __shfl(hw, 0), s1 = __shfl(hw, 1);
        unsigned s2 = __shfl(hw, 2), s3 = __shfl(hw, 3);
        if (lane == 0) {
            u32x2 w; w[0] = s0 | (s1 << 16); w[1] = s2 | (s3 << 16);
            unsigned* dst = exw + (unsigned)(bid * 8 + wv * 2);
            asm volatile("global_store_dwordx2 %0, %1, off sc0 sc1"
                         :: "v"(dst), "v"(w) : "memory");
        }
        if (lane < RPW) {
            __builtin_nontemporal_store(
                hv, &out[(size_t)t * OUT_COLS + r0 + wv * RPW + lane]);
        }
        // No barrier: hl[par] is next written at step t+2, which is gated by
        // remote blocks publishing (t+2)-data; that requires THEIR step-(t+1)
        // poll to have seen OUR block's (t+1)-publish, which every sibling
        // wave emits only after finishing its step-t reads of hl[par].
    }
}

__global__ void init_kernel(unsigned* __restrict__ ex0,
                            unsigned* __restrict__ ex1) {
    int i = blockIdx.x * blockDim.x + threadIdx.x;
    if (i < R_SIZE / 2) {
        ex0[i] = 0u;            // tag 0, h = 0  -> valid initial state, step 0
        ex1[i] = TAG_MASK;      // tag 1 != expected tag 0 at step 1 -> wait
    }
}

__global__ void copy_x_kernel(const float* __restrict__ x, float* __restrict__ out) {
    int i = blockIdx.x * blockDim.x + threadIdx.x;
    if (i < T_STEPS * I_SIZE) {
        int t = i / I_SIZE, c = i % I_SIZE;
        out[(size_t)t * OUT_COLS + R_SIZE + c] = x[i];
    }
}

extern "C" void kernel_launch(void* const* d_in, const int* in_sizes, int n_in,
                              void* d_out, int out_size, void* d_ws, size_t ws_size,
                              hipStream_t stream) {
    // setup_inputs order: x [T,3], Win [R,3], Wh [R,R]; all fp32.
    const float* x   = (const float*)d_in[0];
    const float* Win = (const float*)d_in[1];
    const float* Wh  = (const float*)d_in[2];
    float* out = (float*)d_out;

    // ws layout: two exchange buffers of R/2 dwords (8 KB) each.
    unsigned* ex0 = (unsigned*)d_ws;
    unsigned* ex1 = ex0 + R_SIZE / 2;

    init_kernel<<<dim3((R_SIZE / 2 + BT - 1) / BT), dim3(BT), 0, stream>>>(ex0, ex1);
    copy_x_kernel<<<dim3((T_STEPS * I_SIZE + BT - 1) / BT), dim3(BT), 0, stream>>>(x, out);

    void* args[] = {(void*)&Wh, (void*)&Win, (void*)&x, (void*)&out,
                    (void*)&ex0, (void*)&ex1};
    hipError_t e = hipLaunchCooperativeKernel((void*)esn_kernel, dim3(NB), dim3(BT),
                                              args, 0, stream);
    if (e != hipSuccess) {
        // Fallback: plain launch; 256 blocks x 4 waves always co-resident.
        esn_kernel<<<dim3(NB), dim3(BT), 0, stream>>>(Wh, Win, x, out, ex0, ex1);
    }
}

// Round 6
// 17885.730 us; speedup vs baseline: 1.0350x; 1.0350x over previous
//
#include <hip/hip_runtime.h>
#include <cmath>

// ESN forward scan on MI355X — round 6.
// Rounds 3/4/5 all plateaued at 4.0-4.5 us/step across three different sync
// structures -> fixed latency in the dependency chain, not scheduling. The
// common factor: all my inline-asm polls/publishes used "sc0 sc1". On gfx950
// SC[1:0]={sc1,sc0}: sc1 alone = DEVICE scope (coherence at the MALL);
// sc0+sc1 = SYSTEM scope (round-trip past the MALL). Evidence: FETCH_SIZE
// 600-825 MB = poll traffic on an 8-16 KB exchange buffer hitting HBM.
// Round 6 = round-3 structure (the fastest) with three deltas:
//   1. sc1-only on all polls/publishes (same encoding the compiler emits
//      for known-correct AGENT-scope relaxed atomics).
//   2. 2 B/row exchange, bit14 tag (|h|<1 so bit14 is free); publish =
//      per-lane global_store_short sc1 from lanes 0..3, BEFORE the out
//      store (one instruction, 8 contiguous bytes per wave).
//   3. hl double-buffered -> exactly ONE __syncthreads per step (fixes the
//      round-3 intra-block race without round-4's skew-coupling barrier;
//      the t+2 overwrite of hl[par] is causally gated: sibling waves read
//      hl[par] at t -> publish (t+1) -> remote blocks consume -> publish
//      (t+2) -> our poll sees (t+2) -> only then do we overwrite).
// Unchanged: 256 blocks x 256 thr, Wh fp16 in 128 VGPRs/thread, fp32 leak
// chain, v_dot2 + butterfly reduce, __expf tanh, cooperative launch.

#define T_STEPS  4096
#define R_SIZE   4096
#define I_SIZE   3
#define OUT_COLS (R_SIZE + I_SIZE)   // 4099
#define NB       256                 // blocks == CUs; all co-resident
#define BT       256                 // threads per block (4 waves)
#define RPB      16                  // rows per block
#define RPW      4                   // rows per wave
#define LEAK     0.1f
#define TAG_MASK 0x40004000u         // bit14 of each fp16 half

typedef _Float16 h2 __attribute__((ext_vector_type(2)));
typedef _Float16 h8 __attribute__((ext_vector_type(8)));
typedef unsigned u32x4 __attribute__((ext_vector_type(4)));

__device__ __forceinline__ float fdot2f(h2 a, h2 b, float c) {
#if __has_builtin(__builtin_amdgcn_fdot2)
    return __builtin_amdgcn_fdot2(a, b, c, false);
#else
    return c + (float)a[0] * (float)b[0] + (float)a[1] * (float)b[1];
#endif
}

// 8 dwords (16 rows) in flight, DEVICE scope (sc1: read at the MALL, skip
// stale L1/L2 but do NOT force the HBM round-trip system scope causes).
__device__ __forceinline__ void poll8(const unsigned* p, u32x4& a0, u32x4& a1) {
    asm volatile(
        "global_load_dwordx4 %0, %2, off sc1\n\t"
        "global_load_dwordx4 %1, %2, off offset:16 sc1\n\t"
        "s_waitcnt vmcnt(0)"
        : "=&v"(a0), "=&v"(a1)
        : "v"(p)
        : "memory");
}

__global__ void __launch_bounds__(BT, 1) esn_kernel(
    const float* __restrict__ Wh,   // [R, R] row-major fp32
    const float* __restrict__ Win,  // [R, 3]
    const float* __restrict__ x,    // [T, 3]
    float* __restrict__ out,        // [T, 4099]
    unsigned* __restrict__ ex0,     // exchange buf A: 2048 dwords (2 B/row)
    unsigned* __restrict__ ex1)     // exchange buf B: 2048 dwords
{
    __shared__ alignas(16) _Float16 hl[2][R_SIZE];  // 16 KB, ping-pong

    const int tid  = threadIdx.x;
    const int bid  = blockIdx.x;
    const int wv   = tid >> 6;
    const int lane = tid & 63;
    const int r0   = bid * RPB;

    // ---- one-time: this wave's 4 Wh rows -> fp16 registers ----
    h8 wreg[RPW * 8];
    #pragma unroll
    for (int rr = 0; rr < RPW; ++rr) {
        const float* src = Wh + (size_t)(r0 + wv * RPW + rr) * R_SIZE;
        #pragma unroll
        for (int j = 0; j < 8; ++j) {
            int e = (j * 64 + lane) * 8;
            float4 a = *(const float4*)(src + e);
            float4 b = *(const float4*)(src + e + 4);
            h8 hv;
            hv[0] = (_Float16)a.x; hv[1] = (_Float16)a.y;
            hv[2] = (_Float16)a.z; hv[3] = (_Float16)a.w;
            hv[4] = (_Float16)b.x; hv[5] = (_Float16)b.y;
            hv[6] = (_Float16)b.z; hv[7] = (_Float16)b.w;
            wreg[rr * 8 + j] = hv;
        }
    }

    // publisher lanes (lane<4) cache their row's Win
    float win0 = 0.f, win1 = 0.f, win2 = 0.f;
    if (lane < RPW) {
        int r = r0 + wv * RPW + lane;
        win0 = Win[(size_t)r * I_SIZE + 0];
        win1 = Win[(size_t)r * I_SIZE + 1];
        win2 = Win[(size_t)r * I_SIZE + 2];
    }
    float hown = 0.0f;   // fp32 leak chain, h0 = 0

    // thread tid polls block tid's 16 rows: dwords [tid*8, tid*8+8)
    const unsigned* pr[2] = { ex0 + tid * 8, ex1 + tid * 8 };

    for (int t = 0; t < T_STEPS; ++t) {
        const int par = t & 1;
        unsigned short* __restrict__ exw =
            (unsigned short*)(par ? ex0 : ex1);             // buffer (t+1)&1
        const unsigned tagexp = ((unsigned)t >> 1) & 1u;
        const unsigned tagbit = (((unsigned)t + 1u) >> 1) & 1u;

        const float xt0 = x[t * 3 + 0];
        const float xt1 = x[t * 3 + 1];
        const float xt2 = x[t * 3 + 2];

        // ---- batched poll: 8 dwords (16 rows), every bit14 == tagexp ----
        u32x4 a0, a1;
        for (;;) {
            poll8(pr[par], a0, a1);
            unsigned andv = a0[0] & a0[1] & a0[2] & a0[3]
                          & a1[0] & a1[1] & a1[2] & a1[3];
            unsigned orv  = a0[0] | a0[1] | a0[2] | a0[3]
                          | a1[0] | a1[1] | a1[2] | a1[3];
            bool ok = tagexp ? ((andv & TAG_MASK) == TAG_MASK)
                             : ((orv  & TAG_MASK) == 0u);
            if (ok) break;
            __builtin_amdgcn_s_sleep(1);
        }

        // ---- strip tags, stage 32 B to LDS (parity buffer) ----
        {
            u32x4 s0, s1;
            #pragma unroll
            for (int i = 0; i < 4; ++i) { s0[i] = a0[i] & ~TAG_MASK;
                                          s1[i] = a1[i] & ~TAG_MASK; }
            u32x4* d = (u32x4*)&hl[par][(unsigned)tid * 16];
            d[0] = s0; d[1] = s1;
        }
        __syncthreads();   // the ONLY per-step barrier

        // ---- per-lane h chunk into registers ----
        h8 hreg[8];
        const h8* hl8 = (const h8*)&hl[par][0];
        #pragma unroll
        for (int j = 0; j < 8; ++j) hreg[j] = hl8[j * 64 + lane];

        // ---- 4 rows per wave: register weights, dot2-accumulate ----
        float acc[RPW];
        #pragma unroll
        for (int rr = 0; rr < RPW; ++rr) {
            float a = 0.0f;
            #pragma unroll
            for (int j = 0; j < 8; ++j) {
                h8 w8 = wreg[rr * 8 + j];
                h8 hh = hreg[j];
                a = fdot2f(__builtin_shufflevector(w8, w8, 0, 1),
                           __builtin_shufflevector(hh, hh, 0, 1), a);
                a = fdot2f(__builtin_shufflevector(w8, w8, 2, 3),
                           __builtin_shufflevector(hh, hh, 2, 3), a);
                a = fdot2f(__builtin_shufflevector(w8, w8, 4, 5),
                           __builtin_shufflevector(hh, hh, 4, 5), a);
                a = fdot2f(__builtin_shufflevector(w8, w8, 6, 7),
                           __builtin_shufflevector(hh, hh, 6, 7), a);
            }
            #pragma unroll
            for (int s = 32; s; s >>= 1) a += __shfl_xor(a, s, 64);
            acc[rr] = a;
        }

        // ---- epilogue: lanes 0..3 finish rows, publish FIRST, then out ----
        if (lane < RPW) {
            float a = (lane == 0) ? acc[0]
                    : (lane == 1) ? acc[1]
                    : (lane == 2) ? acc[2] : acc[3];
            float z  = xt0 * win0 + xt1 * win1 + xt2 * win2 + a;
            float e  = __expf(2.0f * z);                 // tanh = 1 - 2/(e+1)
            float hn = 1.0f - __fdividef(2.0f, e + 1.0f);
            float hv = LEAK * hown + (1.0f - LEAK) * hn; // |hv| < 1 by induction
            hown = hv;
            int r = r0 + wv * RPW + lane;
            unsigned short hb = __builtin_bit_cast(unsigned short, (_Float16)hv);
            unsigned hw = (unsigned)hb | (tagbit << 14);
            // publish: one instruction, lanes 0..3 -> 8 contiguous bytes
            asm volatile("global_store_short %0, %1, off sc1"
                         :: "v"(exw + r), "v"(hw) : "memory");
            out[(size_t)t * OUT_COLS + r] = hv;
        }
        // No trailing barrier: hl[par] is next overwritten at t+2, causally
        // gated through every sibling wave's (t+1) publish (see header).
    }
}

__global__ void init_kernel(unsigned* __restrict__ ex0,
                            unsigned* __restrict__ ex1) {
    int i = blockIdx.x * blockDim.x + threadIdx.x;
    if (i < R_SIZE / 2) {
        ex0[i] = 0u;            // tag 0, h = 0 -> valid initial state, step 0
        ex1[i] = TAG_MASK;      // bit14=1 != expected 0 at step 1 -> wait
    }
}

__global__ void copy_x_kernel(const float* __restrict__ x, float* __restrict__ out) {
    int i = blockIdx.x * blockDim.x + threadIdx.x;
    if (i < T_STEPS * I_SIZE) {
        int t = i / I_SIZE, c = i % I_SIZE;
        out[(size_t)t * OUT_COLS + R_SIZE + c] = x[i];
    }
}

extern "C" void kernel_launch(void* const* d_in, const int* in_sizes, int n_in,
                              void* d_out, int out_size, void* d_ws, size_t ws_size,
                              hipStream_t stream) {
    // setup_inputs order: x [T,3], Win [R,3], Wh [R,R]; all fp32.
    const float* x   = (const float*)d_in[0];
    const float* Win = (const float*)d_in[1];
    const float* Wh  = (const float*)d_in[2];
    float* out = (float*)d_out;

    // ws layout: two exchange buffers of R/2 dwords (8 KB) each.
    unsigned* ex0 = (unsigned*)d_ws;
    unsigned* ex1 = ex0 + R_SIZE / 2;

    init_kernel<<<dim3((R_SIZE / 2 + BT - 1) / BT), dim3(BT), 0, stream>>>(ex0, ex1);
    copy_x_kernel<<<dim3((T_STEPS * I_SIZE + BT - 1) / BT), dim3(BT), 0, stream>>>(x, out);

    void* args[] = {(void*)&Wh, (void*)&Win, (void*)&x, (void*)&out,
                    (void*)&ex0, (void*)&ex1};
    hipError_t e = hipLaunchCooperativeKernel((void*)esn_kernel, dim3(NB), dim3(BT),
                                              args, 0, stream);
    if (e != hipSuccess) {
        // Fallback: plain launch; 256 blocks x 4 waves always co-resident.
        esn_kernel<<<dim3(NB), dim3(BT), 0, stream>>>(Wh, Win, x, out, ex0, ex1);
    }
}